// Round 2
// baseline (23601.613 us; speedup 1.0000x reference)
//
#include <hip/hip_runtime.h>
#include <hip/hip_bf16.h>
#include <math.h>

#define T_LEN 512
#define BATCH 128
#define EDIM  256
#define HDIM  256      // per-direction hidden
#define G4    1024     // 4*HDIM gate width
#define HID2  512
#define KTAG  32
#define START_TAG 30
#define END_TAG   31
#define NEGV  -100000.0f

__device__ __forceinline__ float sigf(float x) { return 1.0f / (1.0f + expf(-x)); }
__device__ __forceinline__ float bf2f(unsigned int u) {
    union { unsigned int i; float f; } c; c.i = u << 16; return c.f;
}

// ---------------------------------------------------------------------------
// Pack Whh [1024][256] (row = gate*256+j, col = k) into Wp[k][j][4].
// ---------------------------------------------------------------------------
__global__ void pack_whh(const float* __restrict__ Whh, float* __restrict__ Wp) {
    int idx = blockIdx.x * 256 + threadIdx.x;   // 65536 = 256k * 256j
    int k = idx >> 8, j = idx & 255;
    float4 v;
    v.x = Whh[(0 * 256 + j) * 256 + k];
    v.y = Whh[(1 * 256 + j) * 256 + k];
    v.z = Whh[(2 * 256 + j) * 256 + k];
    v.w = Whh[(3 * 256 + j) * 256 + k];
    ((float4*)Wp)[idx] = v;
}

__global__ void fill_kernel(float* out, int n, float v) {
    int i = blockIdx.x * 256 + threadIdx.x;
    if (i < n) out[i] = v;
}

// ---------------------------------------------------------------------------
// fp32 SGEMM chunk: out_loc[mloc][n] = A[m][:] . W[n][:] + bias[n], N=1024.
// AMODE: 0 = gather emb rows via words (lda=256), 1 = fp32 rows lda=512,
//        2 = bf16 rows lda=512.
// Covers global rows [m0glob, m0glob + gridDim.y*128).
// ---------------------------------------------------------------------------
template <int AMODE>
__global__ __launch_bounds__(256) void gemm_pre(
    const void* __restrict__ A, const int* __restrict__ words,
    const float* __restrict__ W, const float* __restrict__ bias,
    float* __restrict__ out, int K, int m0glob)
{
    __shared__ float As[16][128];
    __shared__ float Bs[16][128];

    const int tid = threadIdx.x;
    const int n0 = blockIdx.x * 128;
    const int mloc0 = blockIdx.y * 128;
    const int tx = tid & 15, ty = tid >> 4;
    const int lm = tid & 127, lk = (tid >> 7) * 8;

    float acc[8][8] = {};

    const float* arowf = nullptr;
    const unsigned short* arowh = nullptr;
    {
        int m = m0glob + mloc0 + lm;
        if (AMODE == 0) {
            int b = m & (BATCH - 1), ts = m >> 7;
            arowf = (const float*)A + (size_t)words[b * T_LEN + ts] * EDIM;
        } else if (AMODE == 1) {
            arowf = (const float*)A + (size_t)m * HID2;
        } else {
            arowh = (const unsigned short*)A + (size_t)m * HID2;
        }
    }
    const float* brow = W + (size_t)(n0 + lm) * K;

    for (int k0 = 0; k0 < K; k0 += 16) {
        float av[8];
        if (AMODE == 2) {
            uint4 r = *(const uint4*)(arowh + k0 + lk);
            av[0] = bf2f(r.x & 0xffffu); av[1] = bf2f(r.x >> 16);
            av[2] = bf2f(r.y & 0xffffu); av[3] = bf2f(r.y >> 16);
            av[4] = bf2f(r.z & 0xffffu); av[5] = bf2f(r.z >> 16);
            av[6] = bf2f(r.w & 0xffffu); av[7] = bf2f(r.w >> 16);
        } else {
            float4 a0 = *(const float4*)(arowf + k0 + lk);
            float4 a1 = *(const float4*)(arowf + k0 + lk + 4);
            av[0] = a0.x; av[1] = a0.y; av[2] = a0.z; av[3] = a0.w;
            av[4] = a1.x; av[5] = a1.y; av[6] = a1.z; av[7] = a1.w;
        }
        float4 bq0 = *(const float4*)(brow + k0 + lk);
        float4 bq1 = *(const float4*)(brow + k0 + lk + 4);
        __syncthreads();
#pragma unroll
        for (int q = 0; q < 8; ++q) As[lk + q][lm] = av[q];
        Bs[lk + 0][lm] = bq0.x; Bs[lk + 1][lm] = bq0.y; Bs[lk + 2][lm] = bq0.z; Bs[lk + 3][lm] = bq0.w;
        Bs[lk + 4][lm] = bq1.x; Bs[lk + 5][lm] = bq1.y; Bs[lk + 6][lm] = bq1.z; Bs[lk + 7][lm] = bq1.w;
        __syncthreads();
#pragma unroll
        for (int kk = 0; kk < 16; ++kk) {
            const float4 av0 = *(const float4*)&As[kk][ty * 8];
            const float4 av1 = *(const float4*)&As[kk][ty * 8 + 4];
            const float4 bv0 = *(const float4*)&Bs[kk][tx * 8];
            const float4 bv1 = *(const float4*)&Bs[kk][tx * 8 + 4];
            float ar[8] = {av0.x, av0.y, av0.z, av0.w, av1.x, av1.y, av1.z, av1.w};
            float br[8] = {bv0.x, bv0.y, bv0.z, bv0.w, bv1.x, bv1.y, bv1.z, bv1.w};
#pragma unroll
            for (int i = 0; i < 8; ++i)
#pragma unroll
                for (int j = 0; j < 8; ++j)
                    acc[i][j] += ar[i] * br[j];
        }
    }

    float bb[8];
#pragma unroll
    for (int j = 0; j < 8; ++j) bb[j] = bias[n0 + tx * 8 + j];
#pragma unroll
    for (int i = 0; i < 8; ++i) {
        size_t row = (size_t)(mloc0 + ty * 8 + i);
        float* orow = out + row * G4 + n0 + tx * 8;
        float4 r0, r1;
        r0.x = acc[i][0] + bb[0]; r0.y = acc[i][1] + bb[1];
        r0.z = acc[i][2] + bb[2]; r0.w = acc[i][3] + bb[3];
        r1.x = acc[i][4] + bb[4]; r1.y = acc[i][5] + bb[5];
        r1.z = acc[i][6] + bb[6]; r1.w = acc[i][7] + bb[7];
        *(float4*)(orow) = r0;
        *(float4*)(orow + 4) = r1;
    }
}

// ---------------------------------------------------------------------------
// LSTM chunk. grid = 128 WGs: wg>>6 = dir (0 fwd, 1 bwd), pair = wg&63.
// Thread j owns h-index j for 2 batches. Processes steps s in [s0, s0+C).
// fwd: t = s, pre local row = s - s0. bwd: t = 511-s, local = C-1-(s-s0).
// LAYER 0: writes h1[t][b][dir*256+j] (fp32 or bf16 per H1BF16).
// LAYER 1: accumulates emission half into emitF (with btag) / emitB.
// Carry h,c via state[dir][{h,c}][128][256]; init zero at s0==0.
// ---------------------------------------------------------------------------
template <int LAYER, int H1BF16>
__global__ __launch_bounds__(256) void lstm_chunk(
    const float* __restrict__ preF, const float* __restrict__ preB,
    const float* __restrict__ WpF, const float* __restrict__ WpB,
    void* __restrict__ h1out,
    float* __restrict__ emitF, float* __restrict__ emitB,
    const float* __restrict__ Wtag, const float* __restrict__ btag,
    float* __restrict__ state, int s0, int C)
{
    const int wg = blockIdx.x;
    const int dir = wg >> 6;
    const int pair = wg & 63;
    const int b0 = pair * 2, b1 = b0 + 1;
    const int j = threadIdx.x;

    const float* pre = dir ? preB : preF;
    const float4* Wp = (const float4*)(dir ? WpB : WpF);

    __shared__ float hs[2][HDIM];
    float* st = state + (size_t)dir * 2 * 128 * 256;

    float c0, c1;
    if (s0 == 0) {
        hs[0][j] = 0.0f; hs[1][j] = 0.0f; c0 = 0.0f; c1 = 0.0f;
    } else {
        hs[0][j] = st[b0 * 256 + j];
        hs[1][j] = st[b1 * 256 + j];
        c0 = st[32768 + b0 * 256 + j];
        c1 = st[32768 + b1 * 256 + j];
    }

    // LAYER 1: this thread's slice of Wtag (dir half) in registers.
    float4 wreg[16];
    float bt = 0.0f;
    int tag = 0, part = 0, bsel = 0;
    if (LAYER == 1) {
        tag = (j >> 2) & 31; part = j & 3; bsel = j >> 7;
        const float* wsrc = Wtag + (size_t)tag * HID2 + dir * HDIM + part * 16;
#pragma unroll
        for (int q = 0; q < 4; ++q)
#pragma unroll
            for (int m = 0; m < 4; ++m)
                wreg[q * 4 + m] = *(const float4*)(wsrc + 64 * q + 4 * m);
        bt = btag[tag];
    }
    __syncthreads();

    for (int s = s0; s < s0 + C; ++s) {
        const int sloc = s - s0;
        const int t = dir ? (T_LEN - 1 - s) : s;
        const int tloc = dir ? (C - 1 - sloc) : sloc;

        const float* prow0 = pre + ((size_t)tloc * BATCH + b0) * G4;
        const float* prow1 = prow0 + G4;
        float ai0 = prow0[j], af0 = prow0[256 + j], ag0 = prow0[512 + j], ao0 = prow0[768 + j];
        float ai1 = prow1[j], af1 = prow1[256 + j], ag1 = prow1[512 + j], ao1 = prow1[768 + j];

#pragma unroll 8
        for (int k4 = 0; k4 < 64; ++k4) {
            const float4 h0v = *(const float4*)&hs[0][k4 * 4];
            const float4 h1v = *(const float4*)&hs[1][k4 * 4];
            const float4 w0 = Wp[(k4 * 4 + 0) * 256 + j];
            const float4 w1 = Wp[(k4 * 4 + 1) * 256 + j];
            const float4 w2 = Wp[(k4 * 4 + 2) * 256 + j];
            const float4 w3 = Wp[(k4 * 4 + 3) * 256 + j];
            ai0 += w0.x * h0v.x + w1.x * h0v.y + w2.x * h0v.z + w3.x * h0v.w;
            af0 += w0.y * h0v.x + w1.y * h0v.y + w2.y * h0v.z + w3.y * h0v.w;
            ag0 += w0.z * h0v.x + w1.z * h0v.y + w2.z * h0v.z + w3.z * h0v.w;
            ao0 += w0.w * h0v.x + w1.w * h0v.y + w2.w * h0v.z + w3.w * h0v.w;
            ai1 += w0.x * h1v.x + w1.x * h1v.y + w2.x * h1v.z + w3.x * h1v.w;
            af1 += w0.y * h1v.x + w1.y * h1v.y + w2.y * h1v.z + w3.y * h1v.w;
            ag1 += w0.z * h1v.x + w1.z * h1v.y + w2.z * h1v.z + w3.z * h1v.w;
            ao1 += w0.w * h1v.x + w1.w * h1v.y + w2.w * h1v.z + w3.w * h1v.w;
        }

        float cn0 = sigf(af0) * c0 + sigf(ai0) * tanhf(ag0);
        float hn0 = sigf(ao0) * tanhf(cn0);
        float cn1 = sigf(af1) * c1 + sigf(ai1) * tanhf(ag1);
        float hn1 = sigf(ao1) * tanhf(cn1);

        __syncthreads();           // all reads of old hs complete
        hs[0][j] = hn0;
        hs[1][j] = hn1;
        c0 = cn0; c1 = cn1;
        __syncthreads();           // new hs visible

        if (LAYER == 0) {
            size_t ob = ((size_t)t * BATCH) * HID2 + dir * HDIM + j;
            if (!H1BF16) {
                float* o = (float*)h1out;
                o[ob + (size_t)b0 * HID2] = hn0;
                o[ob + (size_t)b1 * HID2] = hn1;
            } else {
                __hip_bfloat16* o = (__hip_bfloat16*)h1out;
                o[ob + (size_t)b0 * HID2] = __float2bfloat16(hn0);
                o[ob + (size_t)b1 * HID2] = __float2bfloat16(hn1);
            }
        } else {
            // emission partial: emit_half[t][b][tag] = sum_j wt[tag][j]*h[j]
            float acc = 0.0f;
            const float* hrow = hs[bsel];
            const int base = part * 16;
#pragma unroll
            for (int q = 0; q < 4; ++q)
#pragma unroll
                for (int m = 0; m < 4; ++m) {
                    float4 w = wreg[q * 4 + m];
                    float4 h = *(const float4*)&hrow[base + 64 * q + 4 * m];
                    acc += w.x * h.x + w.y * h.y + w.z * h.z + w.w * h.w;
                }
            acc += __shfl_xor(acc, 1);
            acc += __shfl_xor(acc, 2);
            if (part == 0) {
                int b = bsel ? b1 : b0;
                size_t ei = ((size_t)t * BATCH + b) * KTAG + tag;
                if (dir == 0) emitF[ei] = acc + bt;
                else          emitB[ei] = acc;
            }
        }
    }

    // store carry
    st[b0 * 256 + j] = hs[0][j];
    st[b1 * 256 + j] = hs[1][j];
    st[32768 + b0 * 256 + j] = c0;
    st[32768 + b1 * 256 + j] = c1;
}

// ---------------------------------------------------------------------------
// CRF: logZ, gold, Viterbi + backtrace. One 64-lane wave per batch element.
// ---------------------------------------------------------------------------
__global__ __launch_bounds__(64) void crf_kernel(
    const float* __restrict__ emitF, const float* __restrict__ emitB,
    const float* __restrict__ trans, const int* __restrict__ labels,
    float* __restrict__ diff, float* __restrict__ path_out)
{
    const int b = blockIdx.x;
    const int lane = threadIdx.x;
    const int k = lane & 31;

    __shared__ unsigned char bps[T_LEN][KTAG];
    __shared__ unsigned char pth[T_LEN];

    float trow[KTAG];
#pragma unroll
    for (int p = 0; p < KTAG; ++p) trow[p] = trans[k * KTAG + p];
    const float tend = trans[END_TAG * KTAG + k];

    float dp  = (k == START_TAG) ? 0.0f : NEGV;
    float dpv = dp;

    size_t eidx = (size_t)b * KTAG + k;
    float e = emitF[eidx] + emitB[eidx];
    for (int t = 0; t < T_LEN; ++t) {
        float e_next = 0.0f;
        if (t + 1 < T_LEN) {
            size_t ei = ((size_t)(t + 1) * BATCH + b) * KTAG + k;
            e_next = emitF[ei] + emitB[ei];
        }

        float v[KTAG], w[KTAG];
#pragma unroll
        for (int p = 0; p < KTAG; ++p) {
            float d  = __shfl(dp, p);
            float dv = __shfl(dpv, p);
            v[p] = trow[p] + d;
            w[p] = trow[p] + dv;
        }
        float mx[16];
#pragma unroll
        for (int i = 0; i < 16; ++i) mx[i] = fmaxf(v[i], v[i + 16]);
#pragma unroll
        for (int i = 0; i < 8; ++i) mx[i] = fmaxf(mx[i], mx[i + 8]);
#pragma unroll
        for (int i = 0; i < 4; ++i) mx[i] = fmaxf(mx[i], mx[i + 4]);
        float m = fmaxf(fmaxf(mx[0], mx[1]), fmaxf(mx[2], mx[3]));
        float es[KTAG];
#pragma unroll
        for (int p = 0; p < KTAG; ++p) es[p] = expf(v[p] - m);
#pragma unroll
        for (int i = 0; i < 16; ++i) es[i] += es[i + 16];
#pragma unroll
        for (int i = 0; i < 8; ++i) es[i] += es[i + 8];
#pragma unroll
        for (int i = 0; i < 4; ++i) es[i] += es[i + 4];
        float ssum = (es[0] + es[1]) + (es[2] + es[3]);

        float bvv[16]; int bii[16];
#pragma unroll
        for (int i = 0; i < 16; ++i) {
            bool g = w[i + 16] > w[i];
            bvv[i] = g ? w[i + 16] : w[i];
            bii[i] = g ? i + 16 : i;
        }
#pragma unroll
        for (int i = 0; i < 8; ++i) {
            bool g = bvv[i + 8] > bvv[i];
            bvv[i] = g ? bvv[i + 8] : bvv[i]; bii[i] = g ? bii[i + 8] : bii[i];
        }
#pragma unroll
        for (int i = 0; i < 4; ++i) {
            bool g = bvv[i + 4] > bvv[i];
            bvv[i] = g ? bvv[i + 4] : bvv[i]; bii[i] = g ? bii[i + 4] : bii[i];
        }
#pragma unroll
        for (int i = 0; i < 2; ++i) {
            bool g = bvv[i + 2] > bvv[i];
            bvv[i] = g ? bvv[i + 2] : bvv[i]; bii[i] = g ? bii[i + 2] : bii[i];
        }
        bool g1 = bvv[1] > bvv[0];
        float bm = g1 ? bvv[1] : bvv[0];
        int barg = g1 ? bii[1] : bii[0];

        dp  = e + m + logf(ssum);
        dpv = e + bm;
        if (lane < KTAG) bps[t][k] = (unsigned char)barg;
        e = e_next;
    }

    float fv = dp + tend;
    float mm = fv;
    for (int off = 16; off; off >>= 1) mm = fmaxf(mm, __shfl_xor(mm, off));
    float contrib = (lane < KTAG) ? expf(fv - mm) : 0.0f;   // avoid dup half-wave
    float ss = contrib;
    for (int off = 32; off; off >>= 1) ss += __shfl_xor(ss, off);
    float logZ = mm + logf(ss);

    float bv = dpv + tend; int bi = k;
    for (int off = 16; off; off >>= 1) {
        float ov = __shfl_xor(bv, off);
        int   oi = __shfl_xor(bi, off);
        if (ov > bv || (ov == bv && oi < bi)) { bv = ov; bi = oi; }
    }

    float gsum = 0.0f;
    for (int t = lane; t < T_LEN; t += 64) {
        int cur = labels[b * T_LEN + t];
        int prev = (t > 0) ? labels[b * T_LEN + t - 1] : START_TAG;
        size_t gi = ((size_t)t * BATCH + b) * KTAG + cur;
        gsum += trans[cur * KTAG + prev] + emitF[gi] + emitB[gi];
    }
    if (lane == 0) gsum += trans[END_TAG * KTAG + labels[b * T_LEN + T_LEN - 1]];
    for (int off = 32; off; off >>= 1) gsum += __shfl_xor(gsum, off);

    __syncthreads();
    if (lane == 0) {
        diff[b] = logZ - gsum;
        int tag = bi;
        pth[T_LEN - 1] = (unsigned char)tag;
        for (int t = T_LEN - 2; t >= 0; --t) {
            tag = bps[t + 1][tag];
            pth[t] = (unsigned char)tag;
        }
    }
    __syncthreads();
    for (int t = lane; t < T_LEN; t += 64)
        path_out[(size_t)b * T_LEN + t] = (float)pth[t];
}

__global__ void nll_kernel(const float* __restrict__ diff, float* __restrict__ out) {
    int lane = threadIdx.x;   // 128 threads
    float v = diff[lane];
    __shared__ float red[2];
    for (int off = 32; off; off >>= 1) v += __shfl_xor(v, off);
    if ((lane & 63) == 0) red[lane >> 6] = v;
    __syncthreads();
    if (lane == 0) out[0] = (red[0] + red[1]) / 128.0f;
}

// ---------------------------------------------------------------------------
extern "C" void kernel_launch(void* const* d_in, const int* in_sizes, int n_in,
                              void* d_out, int out_size, void* d_ws, size_t ws_size,
                              hipStream_t stream) {
    (void)in_sizes; (void)n_in;

    const int*   words  = (const int*)d_in[0];
    const int*   labels = (const int*)d_in[1];
    const float* emb    = (const float*)d_in[2];
    const float* Wih0f  = (const float*)d_in[3];
    const float* Whh0f  = (const float*)d_in[4];
    const float* b0f    = (const float*)d_in[5];
    const float* Wih0b  = (const float*)d_in[6];
    const float* Whh0b  = (const float*)d_in[7];
    const float* b0b    = (const float*)d_in[8];
    const float* Wih1f  = (const float*)d_in[9];
    const float* Whh1f  = (const float*)d_in[10];
    const float* b1f    = (const float*)d_in[11];
    const float* Wih1b  = (const float*)d_in[12];
    const float* Whh1b  = (const float*)d_in[13];
    const float* b1b    = (const float*)d_in[14];
    const float* Wtag   = (const float*)d_in[15];
    const float* btag   = (const float*)d_in[16];
    const float* trans  = (const float*)d_in[17];
    float* out = (float*)d_out;
    char* ws = (char*)d_ws;

    const size_t WPB   = (size_t)256 * 256 * 4 * 4;              // 1 MB each
    const size_t EMITB = (size_t)T_LEN * BATCH * KTAG * 4;       // 8.39 MB each
    const size_t STB   = (size_t)2 * 2 * 128 * 256 * 4;          // 0.52 MB
    const size_t H1F32 = (size_t)T_LEN * BATCH * HID2 * 4;       // 134.2 MB
    const size_t H1B16 = H1F32 / 2;                              // 67.1 MB
    const size_t PSTEP = (size_t)BATCH * G4 * 4;                 // 0.524 MB / step

    const size_t base = 4 * WPB + 2 * EMITB + STB + 4096 + 64 * 1024;

    int C = 0, h1bf16 = 0;
    for (int c = 512; c >= 8 && !C; c >>= 1)
        if (base + H1F32 + 2 * (size_t)c * PSTEP <= ws_size) C = c;
    if (!C) {
        h1bf16 = 1;
        for (int c = 512; c >= 8 && !C; c >>= 1)
            if (base + H1B16 + 2 * (size_t)c * PSTEP <= ws_size) C = c;
    }
    if (!C) {  // telemetry: report ws_size (MB) via output
        fill_kernel<<<(out_size + 255) / 256, 256, 0, stream>>>(
            out, out_size, (float)(ws_size >> 20));
        return;
    }

    size_t off = 0;
    auto alloc = [&](size_t bytes) -> char* {
        char* p = ws + off;
        off = (off + bytes + 255) & ~(size_t)255;
        return p;
    };
    float* wp0f = (float*)alloc(WPB);
    float* wp0b = (float*)alloc(WPB);
    float* wp1f = (float*)alloc(WPB);
    float* wp1b = (float*)alloc(WPB);
    float* emF  = (float*)alloc(EMITB);
    float* emB  = (float*)alloc(EMITB);
    float* stat = (float*)alloc(STB);
    float* diff = (float*)alloc(4096);
    void*  h1   = (void*)alloc(h1bf16 ? H1B16 : H1F32);
    float* preF = (float*)alloc((size_t)C * PSTEP);
    float* preB = (float*)alloc((size_t)C * PSTEP);

    pack_whh<<<256, 256, 0, stream>>>(Whh0f, wp0f);
    pack_whh<<<256, 256, 0, stream>>>(Whh0b, wp0b);
    pack_whh<<<256, 256, 0, stream>>>(Whh1f, wp1f);
    pack_whh<<<256, 256, 0, stream>>>(Whh1b, wp1b);

    const int nchunk = T_LEN / C;
    dim3 gg(8, C), gb(256);

    // ---- layer 0 ----
    for (int c = 0; c < nchunk; ++c) {
        int t0f = c * C, t0b = T_LEN - (c + 1) * C;
        gemm_pre<0><<<gg, gb, 0, stream>>>(emb, words, Wih0f, b0f, preF, EDIM, t0f * BATCH);
        gemm_pre<0><<<gg, gb, 0, stream>>>(emb, words, Wih0b, b0b, preB, EDIM, t0b * BATCH);
        if (h1bf16)
            lstm_chunk<0, 1><<<128, 256, 0, stream>>>(preF, preB, wp0f, wp0b, h1,
                nullptr, nullptr, Wtag, btag, stat, c * C, C);
        else
            lstm_chunk<0, 0><<<128, 256, 0, stream>>>(preF, preB, wp0f, wp0b, h1,
                nullptr, nullptr, Wtag, btag, stat, c * C, C);
    }
    // ---- layer 1 (emission fused) ----
    for (int c = 0; c < nchunk; ++c) {
        int t0f = c * C, t0b = T_LEN - (c + 1) * C;
        if (h1bf16) {
            gemm_pre<2><<<gg, gb, 0, stream>>>(h1, nullptr, Wih1f, b1f, preF, HID2, t0f * BATCH);
            gemm_pre<2><<<gg, gb, 0, stream>>>(h1, nullptr, Wih1b, b1b, preB, HID2, t0b * BATCH);
        } else {
            gemm_pre<1><<<gg, gb, 0, stream>>>(h1, nullptr, Wih1f, b1f, preF, HID2, t0f * BATCH);
            gemm_pre<1><<<gg, gb, 0, stream>>>(h1, nullptr, Wih1b, b1b, preB, HID2, t0b * BATCH);
        }
        lstm_chunk<1, 0><<<128, 256, 0, stream>>>(preF, preB, wp1f, wp1b, nullptr,
            emF, emB, Wtag, btag, stat, c * C, C);
    }

    crf_kernel<<<128, 64, 0, stream>>>(emF, emB, trans, labels, diff, out + 1);
    nll_kernel<<<1, 128, 0, stream>>>(diff, out);
}